// Round 7
// baseline (364.439 us; speedup 1.0000x reference)
//
#include <hip/hip_runtime.h>
#include <hip/hip_fp16.h>

#define B_ 4
#define C_ 64
#define H_ 256
#define W_ 320
#define N_ 9
#define TOT (B_*N_*H_*W_)          // 2949120
#define HW_ (H_*W_)                // 81920
#define HWC (H_*W_*C_)             // 5242880

// ws layout: [0, NHWC_HALFS*2) fp16 NHWC image; then folded params (floats)
#define NHWC_HALFS (B_*H_*W_*C_)   // 41,943,040 bytes
#define PRM_OFF_BYTES (NHWC_HALFS*2)
// param floats: [0,128) w0f ; [128,144) b0 ; [144,272) w1f ; [272,280) b1 ; [280,288) simw ; [288] simb

union H2x4U { float4 f; __half2 h[4]; };

__global__ __launch_bounds__(512) void fold_params(
    const float* __restrict__ w0, const float* __restrict__ g0, const float* __restrict__ be0,
    const float* __restrict__ mu0, const float* __restrict__ va0,
    const float* __restrict__ w1, const float* __restrict__ g1, const float* __restrict__ be1,
    const float* __restrict__ mu1, const float* __restrict__ va1,
    const float* __restrict__ sw, const float* __restrict__ sb, float* __restrict__ prm)
{
    int t = threadIdx.x;
    if (t < 128) {
        int o = t >> 3;
        float a = g0[o] / sqrtf(va0[o] + 1e-5f);
        prm[t] = w0[t] * a;
    } else if (t < 144) {
        int o = t - 128;
        float a = g0[o] / sqrtf(va0[o] + 1e-5f);
        prm[128 + o] = be0[o] - mu0[o] * a;
    } else if (t < 272) {
        int i = t - 144;
        int c = i >> 4;
        float a = g1[c] / sqrtf(va1[c] + 1e-5f);
        prm[144 + i] = w1[i] * a;
    } else if (t < 280) {
        int c = t - 272;
        float a = g1[c] / sqrtf(va1[c] + 1e-5f);
        prm[272 + c] = be1[c] - mu1[c] * a;
    } else if (t < 288) {
        prm[t] = sw[t - 280];
    } else if (t == 288) {
        prm[288] = sb[0];
    }
}

// NCHW fp32 -> NHWC fp16 transpose (unchanged).
__global__ __launch_bounds__(256) void nchw_to_nhwc_fp16(const float* __restrict__ in,
                                                         __half* __restrict__ out)
{
    __shared__ unsigned int tile[64 * 34];
    const int blk = blockIdx.x;
    const int b   = blk / (HW_ / 64);
    const int hw0 = (blk % (HW_ / 64)) * 64;
    const int tid = threadIdx.x;
    const int px  = tid & 63;
    const int q   = tid >> 6;

    const float* src = in + (size_t)b * HWC + hw0;
#pragma unroll
    for (int i = 0; i < 8; ++i) {
        int c = i * 8 + q * 2;
        float f0 = src[(size_t)c * HW_ + px];
        float f1 = src[(size_t)(c + 1) * HW_ + px];
        __half2 h = __floats2half2_rn(f0, f1);
        tile[px * 34 + (c >> 1)] = *(unsigned int*)&h;
    }
    __syncthreads();

    __half* dstbase = out + ((size_t)b * HW_ + hw0) * C_;
#pragma unroll
    for (int j = 0; j < 2; ++j) {
        int p  = j * 32 + (tid >> 3);
        int cg = tid & 7;
        const unsigned int* r = &tile[p * 34 + cg * 4];
        uint4 v;
        v.x = r[0]; v.y = r[1]; v.z = r[2]; v.w = r[3];
        *(uint4*)(dstbase + (size_t)p * C_ + cg * 8) = v;
    }
}

__device__ __forceinline__ __half2 bl_acc(__half2 a00, __half2 a01, __half2 a10, __half2 a11,
                                          __half2 r, __half2 wxh, __half2 wyh, __half2 acc)
{
    __half2 top = __hfma2(wxh, __hsub2(a01, a00), a00);
    __half2 bot = __hfma2(wxh, __hsub2(a11, a10), a10);
    __half2 s   = __hfma2(wyh, __hsub2(bot, top), top);
    return __hfma2(s, r, acc);
}

__device__ __forceinline__ float gd_compute(const H2x4U& r, const H2x4U& v00, const H2x4U& v01,
                                            const H2x4U& v10, const H2x4U& v11, float wx, float wy)
{
    __half2 wxh = __float2half2_rn(wx);
    __half2 wyh = __float2half2_rn(wy);
    __half2 acc = __float2half2_rn(0.f);
    acc = bl_acc(v00.h[0], v01.h[0], v10.h[0], v11.h[0], r.h[0], wxh, wyh, acc);
    acc = bl_acc(v00.h[1], v01.h[1], v10.h[1], v11.h[1], r.h[1], wxh, wyh, acc);
    acc = bl_acc(v00.h[2], v01.h[2], v10.h[2], v11.h[2], r.h[2], wxh, wyh, acc);
    acc = bl_acc(v00.h[3], v01.h[3], v10.h[3], v11.h[3], r.h[3], wxh, wyh, acc);
    float2 f = __half22float2(acc);
    return (f.x + f.y) * 0.125f;
}

// One block = 256 pixel-LOCATIONS (b,h,w); loops n=0..8 internally.
// ref slices cached in registers across the n-loop (loaded once, coalesced).
__global__ __launch_bounds__(256, 5) void fwn_main(const __half* __restrict__ img,  // NHWC fp16
                                                   const float* __restrict__ grid,
                                                   const float* __restrict__ prm,
                                                   float* __restrict__ out)
{
    __shared__ float wlds[256][9];    // [local pixel][group]
    __shared__ int   ash[256 * 9];    // per-pixel: o00, dx, dy, wx, wy (pitch 9 -> 2-way max)
    const int tid  = threadIdx.x;
    const int lane = tid & 63;
    const int wv   = tid >> 6;
    const int g    = lane & 7;
    const int sub  = lane >> 3;
    const int g8   = g * 8;
    const int b    = blockIdx.x / (HW_ / 256);          // 320 blocks per batch
    const int hwb  = (blockIdx.x % (HW_ / 256)) * 256;  // pixel-location base
    const int ibase = b * HWC;                          // in halfs

    // ---- load ref slices once: pass pp covers pixel px = wv*64+pp*8+sub, group g ----
    H2x4U refr[8];
#pragma unroll
    for (int pp = 0; pp < 8; ++pp) {
        int px = wv * 64 + pp * 8 + sub;
        refr[pp].f = *(const float4*)(img + ibase + (hwb + px) * C_ + g8);
    }

    const float2* gbase = (const float2*)grid + (size_t)b * (N_ * HW_) + hwb;
    float* obase = out + (size_t)b * (N_ * HW_) + hwb;

    for (int n = 0; n < N_; ++n) {
        // ---- prepass: thread tid computes pixel tid's sample addresses ----
        {
            float2 gxy = gbase[n * HW_ + tid];
            float ix = fminf(fmaxf((gxy.x + 1.f) * (W_ * 0.5f) - 0.5f, 0.f), (float)(W_ - 1));
            float iy = fminf(fmaxf((gxy.y + 1.f) * (H_ * 0.5f) - 0.5f, 0.f), (float)(H_ - 1));
            float x0f = floorf(ix), y0f = floorf(iy);
            int x0 = (int)x0f, y0 = (int)y0f;
            int dx = (x0 < W_ - 1) ? C_ : 0;
            int dy = (y0 < H_ - 1) ? W_ * C_ : 0;
            int r9 = tid * 9;
            ash[r9 + 0] = ibase + (y0 * W_ + x0) * C_;
            ash[r9 + 1] = dx;
            ash[r9 + 2] = dy;
            ash[r9 + 3] = __float_as_int(ix - x0f);
            ash[r9 + 4] = __float_as_int(iy - y0f);
        }
        __syncthreads();

        // ---- gather: 8 passes x (pixel, group) per thread, 4 corner loads each ----
#pragma unroll
        for (int pp = 0; pp < 8; ++pp) {
            int px = wv * 64 + pp * 8 + sub;
            int r9 = px * 9;
            int o  = ash[r9 + 0] + g8;
            int dx = ash[r9 + 1];
            int dy = ash[r9 + 2];
            float wx = __int_as_float(ash[r9 + 3]);
            float wy = __int_as_float(ash[r9 + 4]);
            H2x4U v00, v01, v10, v11;
            v00.f = *(const float4*)(img + o);
            v01.f = *(const float4*)(img + o + dx);
            v10.f = *(const float4*)(img + o + dy);
            v11.f = *(const float4*)(img + o + dx + dy);
            wlds[px][g] = gd_compute(refr[pp], v00, v01, v10, v11, wx, wy);
        }
        __syncthreads();

        // ---- MLP for (n, pixel tid) ----
        float wv8[8];
#pragma unroll
        for (int i = 0; i < 8; ++i) wv8[i] = wlds[tid][i];

        float h0[16];
#pragma unroll
        for (int o = 0; o < 16; ++o) {
            float a = prm[128 + o];
#pragma unroll
            for (int gg = 0; gg < 8; ++gg) a = fmaf(prm[o * 8 + gg], wv8[gg], a);
            h0[o] = fmaxf(a, 0.f);
        }
        float s = prm[288];
#pragma unroll
        for (int c = 0; c < 8; ++c) {
            float a = prm[272 + c];
#pragma unroll
            for (int o = 0; o < 16; ++o) a = fmaf(prm[144 + c * 16 + o], h0[o], a);
            float h1 = fmaxf(a, 0.f);
            s = fmaf(prm[280 + c], h1, s);
        }
        obase[n * HW_ + tid] = 1.f / (1.f + __expf(-s));
        // no extra barrier needed: next iter's ash writes are fenced by the
        // post-prepass sync, and wlds rewrites happen after it too.
    }
}

extern "C" void kernel_launch(void* const* d_in, const int* in_sizes, int n_in,
                              void* d_out, int out_size, void* d_ws, size_t ws_size,
                              hipStream_t stream)
{
    const float* ref   = (const float*)d_in[0];
    const float* grd   = (const float*)d_in[1];
    const float* w0    = (const float*)d_in[2];
    const float* g0    = (const float*)d_in[3];
    const float* be0   = (const float*)d_in[4];
    const float* mu0   = (const float*)d_in[5];
    const float* va0   = (const float*)d_in[6];
    const float* w1    = (const float*)d_in[7];
    const float* g1    = (const float*)d_in[8];
    const float* be1   = (const float*)d_in[9];
    const float* mu1   = (const float*)d_in[10];
    const float* va1   = (const float*)d_in[11];
    const float* sw    = (const float*)d_in[12];
    const float* sb    = (const float*)d_in[13];
    float* out = (float*)d_out;

    __half* img = (__half*)d_ws;
    float* prm  = (float*)((char*)d_ws + PRM_OFF_BYTES);

    fold_params<<<1, 512, 0, stream>>>(w0, g0, be0, mu0, va0, w1, g1, be1, mu1, va1, sw, sb, prm);
    nchw_to_nhwc_fp16<<<B_ * (HW_ / 64), 256, 0, stream>>>(ref, img);
    fwn_main<<<B_ * (HW_ / 256), 256, 0, stream>>>(img, grd, prm, out);
}

// Round 8
// 324.194 us; speedup vs baseline: 1.1241x; 1.1241x over previous
//
#include <hip/hip_runtime.h>
#include <hip/hip_fp16.h>

#define B_ 4
#define C_ 64
#define H_ 256
#define W_ 320
#define N_ 9
#define TOT (B_*N_*H_*W_)          // 2949120
#define HW_ (H_*W_)                // 81920
#define HWC (H_*W_*C_)             // 5242880
#define NPB (N_*HW_)               // pixels per batch = 737280 = 2880 tiles of 256

// ws layout: [0, NHWC_HALFS*2) fp16 NHWC image; then folded params (floats)
#define NHWC_HALFS (B_*H_*W_*C_)   // 41,943,040 bytes
#define PRM_OFF_BYTES (NHWC_HALFS*2)
// param floats: [0,128) w0f ; [128,144) b0 ; [144,272) w1f ; [272,280) b1 ; [280,288) simw ; [288] simb

union H2x4U { float4 f; __half2 h[4]; };

__global__ __launch_bounds__(512) void fold_params(
    const float* __restrict__ w0, const float* __restrict__ g0, const float* __restrict__ be0,
    const float* __restrict__ mu0, const float* __restrict__ va0,
    const float* __restrict__ w1, const float* __restrict__ g1, const float* __restrict__ be1,
    const float* __restrict__ mu1, const float* __restrict__ va1,
    const float* __restrict__ sw, const float* __restrict__ sb, float* __restrict__ prm)
{
    int t = threadIdx.x;
    if (t < 128) {
        int o = t >> 3;
        float a = g0[o] / sqrtf(va0[o] + 1e-5f);
        prm[t] = w0[t] * a;
    } else if (t < 144) {
        int o = t - 128;
        float a = g0[o] / sqrtf(va0[o] + 1e-5f);
        prm[128 + o] = be0[o] - mu0[o] * a;
    } else if (t < 272) {
        int i = t - 144;
        int c = i >> 4;
        float a = g1[c] / sqrtf(va1[c] + 1e-5f);
        prm[144 + i] = w1[i] * a;
    } else if (t < 280) {
        int c = t - 272;
        float a = g1[c] / sqrtf(va1[c] + 1e-5f);
        prm[272 + c] = be1[c] - mu1[c] * a;
    } else if (t < 288) {
        prm[t] = sw[t - 280];
    } else if (t == 288) {
        prm[288] = sb[0];
    }
}

// NCHW fp32 -> NHWC fp16 transpose (unchanged).
__global__ __launch_bounds__(256) void nchw_to_nhwc_fp16(const float* __restrict__ in,
                                                         __half* __restrict__ out)
{
    __shared__ unsigned int tile[64 * 34];
    const int blk = blockIdx.x;
    const int b   = blk / (HW_ / 64);
    const int hw0 = (blk % (HW_ / 64)) * 64;
    const int tid = threadIdx.x;
    const int px  = tid & 63;
    const int q   = tid >> 6;

    const float* src = in + (size_t)b * HWC + hw0;
#pragma unroll
    for (int i = 0; i < 8; ++i) {
        int c = i * 8 + q * 2;
        float f0 = src[(size_t)c * HW_ + px];
        float f1 = src[(size_t)(c + 1) * HW_ + px];
        __half2 h = __floats2half2_rn(f0, f1);
        tile[px * 34 + (c >> 1)] = *(unsigned int*)&h;
    }
    __syncthreads();

    __half* dstbase = out + ((size_t)b * HW_ + hw0) * C_;
#pragma unroll
    for (int j = 0; j < 2; ++j) {
        int p  = j * 32 + (tid >> 3);
        int cg = tid & 7;
        const unsigned int* r = &tile[p * 34 + cg * 4];
        uint4 v;
        v.x = r[0]; v.y = r[1]; v.z = r[2]; v.w = r[3];
        *(uint4*)(dstbase + (size_t)p * C_ + cg * 8) = v;
    }
}

__device__ __forceinline__ __half2 bl_acc(__half2 a00, __half2 a01, __half2 a10, __half2 a11,
                                          __half2 r, __half2 wxh, __half2 wyh, __half2 acc)
{
    __half2 top = __hfma2(wxh, __hsub2(a01, a00), a00);
    __half2 bot = __hfma2(wxh, __hsub2(a11, a10), a10);
    __half2 s   = __hfma2(wyh, __hsub2(bot, top), top);
    return __hfma2(s, r, acc);
}

__device__ __forceinline__ float gd_compute(const H2x4U& r, const H2x4U& v00, const H2x4U& v01,
                                            const H2x4U& v10, const H2x4U& v11, float wx, float wy)
{
    __half2 wxh = __float2half2_rn(wx);
    __half2 wyh = __float2half2_rn(wy);
    __half2 acc = __float2half2_rn(0.f);
    acc = bl_acc(v00.h[0], v01.h[0], v10.h[0], v11.h[0], r.h[0], wxh, wyh, acc);
    acc = bl_acc(v00.h[1], v01.h[1], v10.h[1], v11.h[1], r.h[1], wxh, wyh, acc);
    acc = bl_acc(v00.h[2], v01.h[2], v10.h[2], v11.h[2], r.h[2], wxh, wyh, acc);
    acc = bl_acc(v00.h[3], v01.h[3], v10.h[3], v11.h[3], r.h[3], wxh, wyh, acc);
    float2 f = __half22float2(acc);
    return (f.x + f.y) * 0.125f;
}

// Round-4 body + XCD-pinned batch mapping: xcd=blk&7 owns batch xcd>>1,
// so each XCD's gather working set is ONE 10.5 MB batch image (not 4).
__global__ __launch_bounds__(256) void fwn_main(const __half* __restrict__ img,  // NHWC fp16
                                                const float* __restrict__ grid,
                                                const float* __restrict__ prm,
                                                float* __restrict__ out)
{
    __shared__ float wlds[256][9];    // [local pixel][group]
    __shared__ int   ash[256 * 9];    // per-pixel addr pack: o00,dx,dy,oref,wx,wy
    const int tid  = threadIdx.x;
    const int lane = tid & 63;
    const int wv   = tid >> 6;
    const int g    = lane & 7;
    const int sub  = lane >> 3;
    const int g8   = g * 8;

    // --- XCD-pinned mapping: blockIdx i -> xcd i&7 -> batch (i&7)>>1, slab (i>>3)*2+(i&1)
    const int blk   = blockIdx.x;
    const int xcd   = blk & 7;
    const int batch = xcd >> 1;
    const int slab  = ((blk >> 3) << 1) | (xcd & 1);     // 0..2879
    const int pix0  = batch * NPB + slab * 256;

    // ---------------- prepass: per-pixel address math, once ----------------
    {
        int P = pix0 + tid;
        float2 gxy = ((const float2*)grid)[P];
        float ix = fminf(fmaxf((gxy.x + 1.f) * (W_ * 0.5f) - 0.5f, 0.f), (float)(W_ - 1));
        float iy = fminf(fmaxf((gxy.y + 1.f) * (H_ * 0.5f) - 0.5f, 0.f), (float)(H_ - 1));
        float x0f = floorf(ix), y0f = floorf(iy);
        int x0 = (int)x0f, y0 = (int)y0f;
        int dx = (x0 < W_ - 1) ? C_ : 0;
        int dy = (y0 < H_ - 1) ? W_ * C_ : 0;

        unsigned up = (unsigned)P;
        unsigned w_ = up % W_;
        unsigned t1 = up / W_;
        unsigned h_ = t1 & (H_ - 1);
        // batch is known from the mapping; base uses it directly
        int base = batch * HWC;
        int r9 = tid * 9;
        ash[r9 + 0] = base + (y0 * W_ + x0) * C_;
        ash[r9 + 1] = dx;
        ash[r9 + 2] = dy;
        ash[r9 + 3] = base + (int)(h_ * W_ + w_) * C_;
        ash[r9 + 4] = __float_as_int(ix - x0f);
        ash[r9 + 5] = __float_as_int(iy - y0f);
    }
    __syncthreads();

    // ---------------- phase 1: gathers (2 pixels per iter) ----------------
#pragma unroll
    for (int pp = 0; pp < 8; pp += 2) {
        const int rA = (wv * 64 + pp * 8 + sub) * 9;
        const int rB = rA + 8 * 9;

        int oA  = ash[rA + 0] + g8;
        int dxA = ash[rA + 1];
        int dyA = ash[rA + 2];
        int orA = ash[rA + 3] + g8;
        float wxA = __int_as_float(ash[rA + 4]);
        float wyA = __int_as_float(ash[rA + 5]);
        H2x4U ra, a00, a01, a10, a11;
        ra.f  = *(const float4*)(img + orA);
        a00.f = *(const float4*)(img + oA);
        a01.f = *(const float4*)(img + oA + dxA);
        a10.f = *(const float4*)(img + oA + dyA);
        a11.f = *(const float4*)(img + oA + dxA + dyA);

        int oB  = ash[rB + 0] + g8;
        int dxB = ash[rB + 1];
        int dyB = ash[rB + 2];
        int orB = ash[rB + 3] + g8;
        float wxB = __int_as_float(ash[rB + 4]);
        float wyB = __int_as_float(ash[rB + 5]);
        H2x4U rb, b00, b01, b10, b11;
        rb.f  = *(const float4*)(img + orB);
        b00.f = *(const float4*)(img + oB);
        b01.f = *(const float4*)(img + oB + dxB);
        b10.f = *(const float4*)(img + oB + dyB);
        b11.f = *(const float4*)(img + oB + dxB + dyB);

        wlds[wv * 64 + pp * 8 + sub][g]     = gd_compute(ra, a00, a01, a10, a11, wxA, wyA);
        wlds[wv * 64 + pp * 8 + sub + 8][g] = gd_compute(rb, b00, b01, b10, b11, wxB, wyB);
    }

    __syncthreads();

    // ---------------- phase 2: per-pixel MLP ----------------
    float wv8[8];
#pragma unroll
    for (int i = 0; i < 8; ++i) wv8[i] = wlds[tid][i];

    float h0[16];
#pragma unroll
    for (int o = 0; o < 16; ++o) {
        float a = prm[128 + o];
#pragma unroll
        for (int gg = 0; gg < 8; ++gg) a = fmaf(prm[o * 8 + gg], wv8[gg], a);
        h0[o] = fmaxf(a, 0.f);
    }
    float s = prm[288];
#pragma unroll
    for (int c = 0; c < 8; ++c) {
        float a = prm[272 + c];
#pragma unroll
        for (int o = 0; o < 16; ++o) a = fmaf(prm[144 + c * 16 + o], h0[o], a);
        float h1 = fmaxf(a, 0.f);
        s = fmaf(prm[280 + c], h1, s);
    }
    out[pix0 + tid] = 1.f / (1.f + __expf(-s));
}

extern "C" void kernel_launch(void* const* d_in, const int* in_sizes, int n_in,
                              void* d_out, int out_size, void* d_ws, size_t ws_size,
                              hipStream_t stream)
{
    const float* ref   = (const float*)d_in[0];
    const float* grd   = (const float*)d_in[1];
    const float* w0    = (const float*)d_in[2];
    const float* g0    = (const float*)d_in[3];
    const float* be0   = (const float*)d_in[4];
    const float* mu0   = (const float*)d_in[5];
    const float* va0   = (const float*)d_in[6];
    const float* w1    = (const float*)d_in[7];
    const float* g1    = (const float*)d_in[8];
    const float* be1   = (const float*)d_in[9];
    const float* mu1   = (const float*)d_in[10];
    const float* va1   = (const float*)d_in[11];
    const float* sw    = (const float*)d_in[12];
    const float* sb    = (const float*)d_in[13];
    float* out = (float*)d_out;

    __half* img = (__half*)d_ws;
    float* prm  = (float*)((char*)d_ws + PRM_OFF_BYTES);

    fold_params<<<1, 512, 0, stream>>>(w0, g0, be0, mu0, va0, w1, g1, be1, mu1, va1, sw, sb, prm);
    nchw_to_nhwc_fp16<<<B_ * (HW_ / 64), 256, 0, stream>>>(ref, img);
    fwn_main<<<TOT / 256, 256, 0, stream>>>(img, grd, prm, out);
}

// Round 9
// 313.063 us; speedup vs baseline: 1.1641x; 1.0356x over previous
//
#include <hip/hip_runtime.h>
#include <hip/hip_fp16.h>

#define B_ 4
#define C_ 64
#define H_ 256
#define W_ 320
#define N_ 9
#define TOT (B_*N_*H_*W_)          // 2949120
#define HW_ (H_*W_)                // 81920
#define HWC (H_*W_*C_)             // 5242880
#define NPB (N_*HW_)               // 737280

// ws layout: [0, NHWC_HALFS*2) fp16 NHWC image; then folded params (floats)
#define NHWC_HALFS (B_*H_*W_*C_)   // 41,943,040 bytes
#define PRM_OFF_BYTES (NHWC_HALFS*2)
// param floats: [0,128) w0f ; [128,144) b0 ; [144,272) w1f ; [272,280) b1 ; [280,288) simw ; [288] simb

union H2x4U { float4 f; __half2 h[4]; };

__global__ __launch_bounds__(512) void fold_params(
    const float* __restrict__ w0, const float* __restrict__ g0, const float* __restrict__ be0,
    const float* __restrict__ mu0, const float* __restrict__ va0,
    const float* __restrict__ w1, const float* __restrict__ g1, const float* __restrict__ be1,
    const float* __restrict__ mu1, const float* __restrict__ va1,
    const float* __restrict__ sw, const float* __restrict__ sb, float* __restrict__ prm)
{
    int t = threadIdx.x;
    if (t < 128) {
        int o = t >> 3;
        float a = g0[o] / sqrtf(va0[o] + 1e-5f);
        prm[t] = w0[t] * a;
    } else if (t < 144) {
        int o = t - 128;
        float a = g0[o] / sqrtf(va0[o] + 1e-5f);
        prm[128 + o] = be0[o] - mu0[o] * a;
    } else if (t < 272) {
        int i = t - 144;
        int c = i >> 4;
        float a = g1[c] / sqrtf(va1[c] + 1e-5f);
        prm[144 + i] = w1[i] * a;
    } else if (t < 280) {
        int c = t - 272;
        float a = g1[c] / sqrtf(va1[c] + 1e-5f);
        prm[272 + c] = be1[c] - mu1[c] * a;
    } else if (t < 288) {
        prm[t] = sw[t - 280];
    } else if (t == 288) {
        prm[288] = sb[0];
    }
}

// NCHW fp32 -> NHWC fp16 transpose (unchanged).
__global__ __launch_bounds__(256) void nchw_to_nhwc_fp16(const float* __restrict__ in,
                                                         __half* __restrict__ out)
{
    __shared__ unsigned int tile[64 * 34];
    const int blk = blockIdx.x;
    const int b   = blk / (HW_ / 64);
    const int hw0 = (blk % (HW_ / 64)) * 64;
    const int tid = threadIdx.x;
    const int px  = tid & 63;
    const int q   = tid >> 6;

    const float* src = in + (size_t)b * HWC + hw0;
#pragma unroll
    for (int i = 0; i < 8; ++i) {
        int c = i * 8 + q * 2;
        float f0 = src[(size_t)c * HW_ + px];
        float f1 = src[(size_t)(c + 1) * HW_ + px];
        __half2 h = __floats2half2_rn(f0, f1);
        tile[px * 34 + (c >> 1)] = *(unsigned int*)&h;
    }
    __syncthreads();

    __half* dstbase = out + ((size_t)b * HW_ + hw0) * C_;
#pragma unroll
    for (int j = 0; j < 2; ++j) {
        int p  = j * 32 + (tid >> 3);
        int cg = tid & 7;
        const unsigned int* r = &tile[p * 34 + cg * 4];
        uint4 v;
        v.x = r[0]; v.y = r[1]; v.z = r[2]; v.w = r[3];
        *(uint4*)(dstbase + (size_t)p * C_ + cg * 8) = v;
    }
}

__device__ __forceinline__ __half2 bl_acc(__half2 a00, __half2 a01, __half2 a10, __half2 a11,
                                          __half2 r, __half2 wxh, __half2 wyh, __half2 acc)
{
    __half2 top = __hfma2(wxh, __hsub2(a01, a00), a00);
    __half2 bot = __hfma2(wxh, __hsub2(a11, a10), a10);
    __half2 s   = __hfma2(wyh, __hsub2(bot, top), top);
    return __hfma2(s, r, acc);
}

__device__ __forceinline__ float gd_compute(const H2x4U& r, const H2x4U& v00, const H2x4U& v01,
                                            const H2x4U& v10, const H2x4U& v11, float wx, float wy)
{
    __half2 wxh = __float2half2_rn(wx);
    __half2 wyh = __float2half2_rn(wy);
    __half2 acc = __float2half2_rn(0.f);
    acc = bl_acc(v00.h[0], v01.h[0], v10.h[0], v11.h[0], r.h[0], wxh, wyh, acc);
    acc = bl_acc(v00.h[1], v01.h[1], v10.h[1], v11.h[1], r.h[1], wxh, wyh, acc);
    acc = bl_acc(v00.h[2], v01.h[2], v10.h[2], v11.h[2], r.h[2], wxh, wyh, acc);
    acc = bl_acc(v00.h[3], v01.h[3], v10.h[3], v11.h[3], r.h[3], wxh, wyh, acc);
    float2 f = __half22float2(acc);
    return (f.x + f.y) * 0.125f;
}

// Location-major (r7 body, ref in registers across the n-loop) + XCD-batch pin:
// xcd = blk&7 -> batch = xcd>>1, so each XCD's gather working set is ONE batch
// image (10.5 MB) even though all 1280 blocks are co-resident.
__global__ __launch_bounds__(256, 5) void fwn_main(const __half* __restrict__ img,  // NHWC fp16
                                                   const float* __restrict__ grid,
                                                   const float* __restrict__ prm,
                                                   float* __restrict__ out)
{
    __shared__ float wlds[256][9];    // [local pixel][group]
    __shared__ int   ash[256 * 9];    // per-pixel: o00, dx, dy, wx, wy
    const int tid  = threadIdx.x;
    const int lane = tid & 63;
    const int wv   = tid >> 6;
    const int g    = lane & 7;
    const int sub  = lane >> 3;
    const int g8   = g * 8;

    // --- XCD-pinned mapping: 1280 blocks; xcd=blk&7 -> batch; slab 0..319
    const int blk  = blockIdx.x;
    const int xcd  = blk & 7;
    const int b    = xcd >> 1;
    const int slab = ((blk >> 3) << 1) | (xcd & 1);     // 0..319
    const int hwb  = slab * 256;                        // pixel-location base
    const int ibase = b * HWC;                          // in halfs

    // ---- load ref slices once: pass pp covers pixel px = wv*64+pp*8+sub, group g ----
    H2x4U refr[8];
#pragma unroll
    for (int pp = 0; pp < 8; ++pp) {
        int px = wv * 64 + pp * 8 + sub;
        refr[pp].f = *(const float4*)(img + ibase + (hwb + px) * C_ + g8);
    }

    const float2* gbase = (const float2*)grid + (size_t)b * NPB + hwb;
    float* obase = out + (size_t)b * NPB + hwb;

    for (int n = 0; n < N_; ++n) {
        // ---- prepass: thread tid computes pixel tid's sample addresses ----
        {
            float2 gxy = gbase[n * HW_ + tid];
            float ix = fminf(fmaxf((gxy.x + 1.f) * (W_ * 0.5f) - 0.5f, 0.f), (float)(W_ - 1));
            float iy = fminf(fmaxf((gxy.y + 1.f) * (H_ * 0.5f) - 0.5f, 0.f), (float)(H_ - 1));
            float x0f = floorf(ix), y0f = floorf(iy);
            int x0 = (int)x0f, y0 = (int)y0f;
            int dx = (x0 < W_ - 1) ? C_ : 0;
            int dy = (y0 < H_ - 1) ? W_ * C_ : 0;
            int r9 = tid * 9;
            ash[r9 + 0] = ibase + (y0 * W_ + x0) * C_;
            ash[r9 + 1] = dx;
            ash[r9 + 2] = dy;
            ash[r9 + 3] = __float_as_int(ix - x0f);
            ash[r9 + 4] = __float_as_int(iy - y0f);
        }
        __syncthreads();

        // ---- gather: 8 passes x (pixel, group) per thread, 4 corner loads each ----
#pragma unroll
        for (int pp = 0; pp < 8; ++pp) {
            int px = wv * 64 + pp * 8 + sub;
            int r9 = px * 9;
            int o  = ash[r9 + 0] + g8;
            int dx = ash[r9 + 1];
            int dy = ash[r9 + 2];
            float wx = __int_as_float(ash[r9 + 3]);
            float wy = __int_as_float(ash[r9 + 4]);
            H2x4U v00, v01, v10, v11;
            v00.f = *(const float4*)(img + o);
            v01.f = *(const float4*)(img + o + dx);
            v10.f = *(const float4*)(img + o + dy);
            v11.f = *(const float4*)(img + o + dx + dy);
            wlds[px][g] = gd_compute(refr[pp], v00, v01, v10, v11, wx, wy);
        }
        __syncthreads();

        // ---- MLP for (n, pixel tid) ----
        float wv8[8];
#pragma unroll
        for (int i = 0; i < 8; ++i) wv8[i] = wlds[tid][i];

        float h0[16];
#pragma unroll
        for (int o = 0; o < 16; ++o) {
            float a = prm[128 + o];
#pragma unroll
            for (int gg = 0; gg < 8; ++gg) a = fmaf(prm[o * 8 + gg], wv8[gg], a);
            h0[o] = fmaxf(a, 0.f);
        }
        float s = prm[288];
#pragma unroll
        for (int c = 0; c < 8; ++c) {
            float a = prm[272 + c];
#pragma unroll
            for (int o = 0; o < 16; ++o) a = fmaf(prm[144 + c * 16 + o], h0[o], a);
            float h1 = fmaxf(a, 0.f);
            s = fmaf(prm[280 + c], h1, s);
        }
        obase[n * HW_ + tid] = 1.f / (1.f + __expf(-s));
    }
}

extern "C" void kernel_launch(void* const* d_in, const int* in_sizes, int n_in,
                              void* d_out, int out_size, void* d_ws, size_t ws_size,
                              hipStream_t stream)
{
    const float* ref   = (const float*)d_in[0];
    const float* grd   = (const float*)d_in[1];
    const float* w0    = (const float*)d_in[2];
    const float* g0    = (const float*)d_in[3];
    const float* be0   = (const float*)d_in[4];
    const float* mu0   = (const float*)d_in[5];
    const float* va0   = (const float*)d_in[6];
    const float* w1    = (const float*)d_in[7];
    const float* g1    = (const float*)d_in[8];
    const float* be1   = (const float*)d_in[9];
    const float* mu1   = (const float*)d_in[10];
    const float* va1   = (const float*)d_in[11];
    const float* sw    = (const float*)d_in[12];
    const float* sb    = (const float*)d_in[13];
    float* out = (float*)d_out;

    __half* img = (__half*)d_ws;
    float* prm  = (float*)((char*)d_ws + PRM_OFF_BYTES);

    fold_params<<<1, 512, 0, stream>>>(w0, g0, be0, mu0, va0, w1, g1, be1, mu1, va1, sw, sb, prm);
    nchw_to_nhwc_fp16<<<B_ * (HW_ / 64), 256, 0, stream>>>(ref, img);
    fwn_main<<<B_ * (HW_ / 256), 256, 0, stream>>>(img, grd, prm, out);
}

// Round 10
// 309.048 us; speedup vs baseline: 1.1792x; 1.0130x over previous
//
#include <hip/hip_runtime.h>
#include <hip/hip_fp16.h>

#define B_ 4
#define C_ 64
#define H_ 256
#define W_ 320
#define N_ 9
#define TOT (B_*N_*H_*W_)          // 2949120
#define HW_ (H_*W_)                // 81920
#define HWC (H_*W_*C_)             // 5242880
#define NPB (N_*HW_)               // 737280
#define SMP 2304                   // samples per block = 256 px * 9 n

// ws layout: [0, NHWC_HALFS*2) fp16 NHWC image; then folded params (floats)
#define NHWC_HALFS (B_*H_*W_*C_)   // 41,943,040 bytes
#define PRM_OFF_BYTES (NHWC_HALFS*2)
// param floats: [0,128) w0f ; [128,144) b0 ; [144,272) w1f ; [272,280) b1 ; [280,288) simw ; [288] simb

union H2x4U { float4 f; __half2 h[4]; };

__global__ __launch_bounds__(512) void fold_params(
    const float* __restrict__ w0, const float* __restrict__ g0, const float* __restrict__ be0,
    const float* __restrict__ mu0, const float* __restrict__ va0,
    const float* __restrict__ w1, const float* __restrict__ g1, const float* __restrict__ be1,
    const float* __restrict__ mu1, const float* __restrict__ va1,
    const float* __restrict__ sw, const float* __restrict__ sb, float* __restrict__ prm)
{
    int t = threadIdx.x;
    if (t < 128) {
        int o = t >> 3;
        float a = g0[o] / sqrtf(va0[o] + 1e-5f);
        prm[t] = w0[t] * a;
    } else if (t < 144) {
        int o = t - 128;
        float a = g0[o] / sqrtf(va0[o] + 1e-5f);
        prm[128 + o] = be0[o] - mu0[o] * a;
    } else if (t < 272) {
        int i = t - 144;
        int c = i >> 4;
        float a = g1[c] / sqrtf(va1[c] + 1e-5f);
        prm[144 + i] = w1[i] * a;
    } else if (t < 280) {
        int c = t - 272;
        float a = g1[c] / sqrtf(va1[c] + 1e-5f);
        prm[272 + c] = be1[c] - mu1[c] * a;
    } else if (t < 288) {
        prm[t] = sw[t - 280];
    } else if (t == 288) {
        prm[288] = sb[0];
    }
}

// NCHW fp32 -> NHWC fp16 transpose (unchanged).
__global__ __launch_bounds__(256) void nchw_to_nhwc_fp16(const float* __restrict__ in,
                                                         __half* __restrict__ out)
{
    __shared__ unsigned int tile[64 * 34];
    const int blk = blockIdx.x;
    const int b   = blk / (HW_ / 64);
    const int hw0 = (blk % (HW_ / 64)) * 64;
    const int tid = threadIdx.x;
    const int px  = tid & 63;
    const int q   = tid >> 6;

    const float* src = in + (size_t)b * HWC + hw0;
#pragma unroll
    for (int i = 0; i < 8; ++i) {
        int c = i * 8 + q * 2;
        float f0 = src[(size_t)c * HW_ + px];
        float f1 = src[(size_t)(c + 1) * HW_ + px];
        __half2 h = __floats2half2_rn(f0, f1);
        tile[px * 34 + (c >> 1)] = *(unsigned int*)&h;
    }
    __syncthreads();

    __half* dstbase = out + ((size_t)b * HW_ + hw0) * C_;
#pragma unroll
    for (int j = 0; j < 2; ++j) {
        int p  = j * 32 + (tid >> 3);
        int cg = tid & 7;
        const unsigned int* r = &tile[p * 34 + cg * 4];
        uint4 v;
        v.x = r[0]; v.y = r[1]; v.z = r[2]; v.w = r[3];
        *(uint4*)(dstbase + (size_t)p * C_ + cg * 8) = v;
    }
}

__device__ __forceinline__ __half2 bl_acc(__half2 a00, __half2 a01, __half2 a10, __half2 a11,
                                          __half2 r, __half2 wxh, __half2 wyh, __half2 acc)
{
    __half2 top = __hfma2(wxh, __hsub2(a01, a00), a00);
    __half2 bot = __hfma2(wxh, __hsub2(a11, a10), a10);
    __half2 s   = __hfma2(wyh, __hsub2(bot, top), top);
    return __hfma2(s, r, acc);
}

__device__ __forceinline__ float gd_compute(const H2x4U& r, const H2x4U& v00, const H2x4U& v01,
                                            const H2x4U& v10, const H2x4U& v11, float wx, float wy)
{
    __half2 wxh = __float2half2_rn(wx);
    __half2 wyh = __float2half2_rn(wy);
    __half2 acc = __float2half2_rn(0.f);
    acc = bl_acc(v00.h[0], v01.h[0], v10.h[0], v11.h[0], r.h[0], wxh, wyh, acc);
    acc = bl_acc(v00.h[1], v01.h[1], v10.h[1], v11.h[1], r.h[1], wxh, wyh, acc);
    acc = bl_acc(v00.h[2], v01.h[2], v10.h[2], v11.h[2], r.h[2], wxh, wyh, acc);
    acc = bl_acc(v00.h[3], v01.h[3], v10.h[3], v11.h[3], r.h[3], wxh, wyh, acc);
    float2 f = __half22float2(acc);
    return (f.x + f.y) * 0.125f;
}

// Stripe-sorted gather: block's 2304 samples counting-sorted by y0>>6 (4 stripes
// of 64 rows = 2.6 MB each) so co-resident blocks sweep the image stripe-by-stripe
// and the per-XCD gather working set stays ~L2-resident. XCD-batch pin kept.
__global__ __launch_bounds__(256, 4) void fwn_main(const __half* __restrict__ img,  // NHWC fp16
                                                   const float* __restrict__ grid,
                                                   const float* __restrict__ prm,
                                                   float* __restrict__ out)
{
    __shared__ unsigned int recA[SMP];          // o00_rel | dxbit<<23 | dybit<<24
    __shared__ unsigned int recB[SMP];          // (wx,wy) as half2
    __shared__ unsigned short sidA[SMP];        // n<<8 | px
    __shared__ float wlds[256][9];              // per-chunk weights [slot][group]
    __shared__ unsigned long long waveTot[4];

    const int tid  = threadIdx.x;
    const int lane = tid & 63;
    const int wv   = tid >> 6;
    const int g    = lane & 7;
    const int sub  = lane >> 3;
    const int g8   = g * 8;

    // --- XCD-pinned mapping: 1280 blocks; xcd=blk&7 -> batch; slab 0..319
    const int blk  = blockIdx.x;
    const int xcd  = blk & 7;
    const int b    = xcd >> 1;
    const int slab = ((blk >> 3) << 1) | (xcd & 1);
    const int hwb  = slab * 256;
    const int ibase = b * HWC;                  // halfs

    const float2* gbase = (const float2*)grid + (size_t)b * NPB + hwb;
    float* obase = out + (size_t)b * NPB + hwb;

    // ---------------- prepass: addresses + stripe counts ----------------
    unsigned int w0s[9], w1s[9];
    int ss[9];
    unsigned int cnt[4] = {0, 0, 0, 0};
#pragma unroll
    for (int n = 0; n < N_; ++n) {
        float2 gxy = gbase[n * HW_ + tid];
        float ix = fminf(fmaxf((gxy.x + 1.f) * (W_ * 0.5f) - 0.5f, 0.f), (float)(W_ - 1));
        float iy = fminf(fmaxf((gxy.y + 1.f) * (H_ * 0.5f) - 0.5f, 0.f), (float)(H_ - 1));
        float x0f = floorf(ix), y0f = floorf(iy);
        int x0 = (int)x0f, y0 = (int)y0f;
        unsigned int w0 = (unsigned int)((y0 * W_ + x0) * C_);
        if (x0 < W_ - 1) w0 |= 1u << 23;
        if (y0 < H_ - 1) w0 |= 1u << 24;
        __half2 wxy = __floats2half2_rn(ix - x0f, iy - y0f);
        w0s[n] = w0;
        w1s[n] = *(unsigned int*)&wxy;
        int st = y0 >> 6;
        ss[n] = st;
        cnt[st]++;
    }

    // packed 4x16-bit block-wide exclusive prefix (wave shfl scan + wave totals)
    unsigned long long pk = (unsigned long long)cnt[0] | ((unsigned long long)cnt[1] << 16)
                          | ((unsigned long long)cnt[2] << 32) | ((unsigned long long)cnt[3] << 48);
    unsigned long long inc = pk;
#pragma unroll
    for (int d = 1; d < 64; d <<= 1) {
        unsigned long long o = __shfl_up(inc, d, 64);
        if (lane >= d) inc += o;
    }
    if (lane == 63) waveTot[wv] = inc;
    __syncthreads();
    unsigned long long wbase = 0, tot = 0;
#pragma unroll
    for (int w = 0; w < 4; ++w) {
        unsigned long long t = waveTot[w];
        if (w < wv) wbase += t;
        tot += t;
    }
    unsigned int bbase[4];
    bbase[0] = 0;
    bbase[1] = (unsigned int)(tot & 0xFFFF);
    bbase[2] = bbase[1] + (unsigned int)((tot >> 16) & 0xFFFF);
    bbase[3] = bbase[2] + (unsigned int)((tot >> 32) & 0xFFFF);
    unsigned long long excl = wbase + inc - pk;

    unsigned int run[4] = {0, 0, 0, 0};
#pragma unroll
    for (int n = 0; n < N_; ++n) {
        int st = ss[n];
        unsigned int pos = bbase[st] + (unsigned int)((excl >> (16 * st)) & 0xFFFF) + run[st];
        run[st]++;
        recA[pos] = w0s[n];
        recB[pos] = w1s[n];
        sidA[pos] = (unsigned short)((n << 8) | tid);
    }
    __syncthreads();

    // ---------------- 9 chunks: gather (stripe-sorted) then MLP ----------------
    for (int ch = 0; ch < 9; ++ch) {
#pragma unroll
        for (int pp = 0; pp < 8; ++pp) {
            int lslot = wv * 64 + pp * 8 + sub;
            int slot  = ch * 256 + lslot;
            unsigned int w0 = recA[slot];
            unsigned int w1 = recB[slot];
            int sid = sidA[slot];
            int o  = ibase + (int)(w0 & 0x7FFFFF) + g8;
            int dx = (w0 & (1u << 23)) ? C_ : 0;
            int dy = (w0 & (1u << 24)) ? W_ * C_ : 0;
            __half2 wxy = *(__half2*)&w1;
            float wx = __half2float(__low2half(wxy));
            float wy = __half2float(__high2half(wxy));

            H2x4U r_, v00, v01, v10, v11;
            r_.f  = *(const float4*)(img + ibase + (hwb + (sid & 255)) * C_ + g8);
            v00.f = *(const float4*)(img + o);
            v01.f = *(const float4*)(img + o + dx);
            v10.f = *(const float4*)(img + o + dy);
            v11.f = *(const float4*)(img + o + dx + dy);
            wlds[lslot][g] = gd_compute(r_, v00, v01, v10, v11, wx, wy);
        }
        __syncthreads();

        // MLP for slot ch*256+tid
        {
            int sid = sidA[ch * 256 + tid];
            float wv8[8];
#pragma unroll
            for (int i = 0; i < 8; ++i) wv8[i] = wlds[tid][i];

            float h0[16];
#pragma unroll
            for (int o = 0; o < 16; ++o) {
                float a = prm[128 + o];
#pragma unroll
                for (int gg = 0; gg < 8; ++gg) a = fmaf(prm[o * 8 + gg], wv8[gg], a);
                h0[o] = fmaxf(a, 0.f);
            }
            float s = prm[288];
#pragma unroll
            for (int c = 0; c < 8; ++c) {
                float a = prm[272 + c];
#pragma unroll
                for (int o = 0; o < 16; ++o) a = fmaf(prm[144 + c * 16 + o], h0[o], a);
                float h1 = fmaxf(a, 0.f);
                s = fmaf(prm[280 + c], h1, s);
            }
            obase[(sid >> 8) * HW_ + (sid & 255)] = 1.f / (1.f + __expf(-s));
        }
        __syncthreads();
    }
}

extern "C" void kernel_launch(void* const* d_in, const int* in_sizes, int n_in,
                              void* d_out, int out_size, void* d_ws, size_t ws_size,
                              hipStream_t stream)
{
    const float* ref   = (const float*)d_in[0];
    const float* grd   = (const float*)d_in[1];
    const float* w0    = (const float*)d_in[2];
    const float* g0    = (const float*)d_in[3];
    const float* be0   = (const float*)d_in[4];
    const float* mu0   = (const float*)d_in[5];
    const float* va0   = (const float*)d_in[6];
    const float* w1    = (const float*)d_in[7];
    const float* g1    = (const float*)d_in[8];
    const float* be1   = (const float*)d_in[9];
    const float* mu1   = (const float*)d_in[10];
    const float* va1   = (const float*)d_in[11];
    const float* sw    = (const float*)d_in[12];
    const float* sb    = (const float*)d_in[13];
    float* out = (float*)d_out;

    __half* img = (__half*)d_ws;
    float* prm  = (float*)((char*)d_ws + PRM_OFF_BYTES);

    fold_params<<<1, 512, 0, stream>>>(w0, g0, be0, mu0, va0, w1, g1, be1, mu1, va1, sw, sb, prm);
    nchw_to_nhwc_fp16<<<B_ * (HW_ / 64), 256, 0, stream>>>(ref, img);
    fwn_main<<<B_ * (HW_ / 256), 256, 0, stream>>>(img, grd, prm, out);
}